// Round 1
// baseline (1341.696 us; speedup 1.0000x reference)
//
#include <hip/hip_runtime.h>
#include <hip/hip_bf16.h>

#define BS 8
#define HID 64
#define NV 1024
#define NSTEP 64

// out layout (float32, concatenated flat, element offsets):
//   imps  [8][1][1024][64]  at 0
//   preds [8][1][1024][64]  at 524288
//   reprs [8][64][1024][64] at 1048576
#define IMPS_OFF  0
#define PREDS_OFF 524288
#define REPRS_OFF 1048576

typedef unsigned short u16;
typedef __attribute__((ext_vector_type(8))) short bf8;   // 8 bf16 = one MFMA operand
typedef __attribute__((ext_vector_type(4))) float f4;    // 4 f32 accumulator

__device__ __forceinline__ u16 f2bf(float f){
    __hip_bfloat16 h = __float2bfloat16(f);
    return *reinterpret_cast<u16*>(&h);
}
// 8 packed bf16 (uint4) -> 8 f32
__device__ __forceinline__ void cv8(uint4 u, float* o){
    o[0] = __uint_as_float(u.x << 16); o[1] = __uint_as_float(u.x & 0xffff0000u);
    o[2] = __uint_as_float(u.y << 16); o[3] = __uint_as_float(u.y & 0xffff0000u);
    o[4] = __uint_as_float(u.z << 16); o[5] = __uint_as_float(u.z & 0xffff0000u);
    o[6] = __uint_as_float(u.w << 16); o[7] = __uint_as_float(u.w & 0xffff0000u);
}

// ---------------- convert f32 inputs -> bf16 working copies ----------------
__global__ void conv_k(const float* __restrict__ g, const float* __restrict__ ig,
                       const float* __restrict__ whh, const float* __restrict__ h0,
                       u16* __restrict__ g_b, u16* __restrict__ ig_b,
                       u16* __restrict__ whh_b, u16* __restrict__ hws){
    int gid = blockIdx.x * blockDim.x + threadIdx.x;
    int nt = gridDim.x * blockDim.x;
    for (int i = gid; i < NV*NV; i += nt){ g_b[i] = f2bf(g[i]); ig_b[i] = f2bf(ig[i]); }
    for (int i = gid; i < 192*64; i += nt) whh_b[i] = f2bf(whh[i]);
    for (int i = gid; i < BS*HID*NV; i += nt) hws[i] = f2bf(h0[i & (HID*NV - 1)]);
}

// ---------------- pre-transpose x/mask: xmt[b][t][v] = mask ? x : +INF ----------------
// grid: 128 blocks = 8 batches x 16 v-tiles of 64, 256 threads
__global__ void prep_k(const float* __restrict__ x, const int* __restrict__ mask,
                       float* __restrict__ xmt){
    __shared__ float tx[64][65];
    __shared__ int   tm[64][65];
    int b  = blockIdx.x >> 4;
    int v0 = (blockIdx.x & 15) << 6;
    int tid = threadIdx.x;
    int q = tid >> 6, l = tid & 63;
    #pragma unroll 4
    for (int r = 0; r < 16; ++r){
        int vv = r*4 + q;
        size_t idx = ((size_t)b*NV + v0 + vv)*64 + l;   // x[b][0][v][t], coalesced in t
        tx[vv][l] = x[idx];
        tm[vv][l] = mask[idx];
    }
    __syncthreads();
    #pragma unroll 4
    for (int r = 0; r < 16; ++r){
        int tt = r*4 + q;
        float xv = tx[l][tt];
        xmt[((size_t)b*NSTEP + tt)*NV + v0 + l] = tm[l][tt] ? xv : __builtin_inff();
    }
}

// ---------------- preds[t=0] = W_init . h0 + b_init (f32) ----------------
__global__ void init_k(const float* __restrict__ h0, const float* __restrict__ Wini,
                       const float* __restrict__ bini, float* __restrict__ out,
                       float* __restrict__ predsT){
    int v = blockIdx.x * blockDim.x + threadIdx.x;
    if (v < NV){
        float s = 0.f;
        for (int h = 0; h < HID; ++h) s += h0[h*NV + v] * Wini[h];
        s += bini[0];
        for (int b = 0; b < BS; ++b){
            out[PREDS_OFF + (size_t)b*65536 + (size_t)v*64] = s;
            predsT[(size_t)b*NSTEP*NV + v] = s;
        }
    }
}

// ---------------- one recurrence step (MFMA, barrier-free K-loop) ----------------
// grid: 256 blocks = 8 batches x 32 node-tiles (32 nodes), 256 threads (4 waves)
__global__ __launch_bounds__(256) void step_k(
    int t,
    const u16* __restrict__ hin, u16* __restrict__ hout,
    const u16* __restrict__ g_b, const u16* __restrict__ ig_b,
    const u16* __restrict__ whh_b,
    const float* __restrict__ xmt, float* __restrict__ predsT,
    const float* __restrict__ Wih, const float* __restrict__ bih,
    const float* __restrict__ bhh,
    const float* __restrict__ Wini, const float* __restrict__ bini,
    const float* __restrict__ Wo, const float* __restrict__ bo,
    float* out, float* __restrict__ rtmp, int staged)
{
    __shared__ float xh_s[NV];                          // 4 KB
    __shared__ __align__(16) u16 hdb[32][72];           // 4.6 KB  h_diff bf16 [w][h]
    __shared__ __align__(16) float hnf[32][68];         // 8.7 KB  h_new  f32 [w][h]
    __shared__ float xg_s[32];
    __shared__ float r1[8][33], r2[8][33];

    const int tid  = threadIdx.x;
    const int b    = blockIdx.x >> 5;
    const int w0   = (blockIdx.x & 31) << 5;
    const int lane = tid & 63;
    const int wv   = tid >> 6;       // wave id 0..3
    const int m16  = lane & 15;
    const int quad = lane >> 4;

    // ---- phase 0a: issue coalesced x_hat input loads (consumed after phase 2) ----
    const int v4 = tid * 4;
    const float* xr = xmt    + ((size_t)b*NSTEP + t)*NV;
    const float* pr = predsT + ((size_t)b*NSTEP + t)*NV;
    float4 xm = *(const float4*)(xr + v4);
    float4 pv = *(const float4*)(pr + v4);

    // ---- phase 2: h_diff = h . graph^T via MFMA, operands DIRECT from global ----
    // A fragment: row wv*16+m16 of h_b; B fragments: rows w0+m16 / w0+16+m16 of graph.
    // Lanes {l, l+16, l+32, l+48} read 64 contiguous bytes of one row -> 64B txns.
    // All 96 loads have compile-time immediate offsets (k*64B <= 1984 < 4096).
    const u16* hb  = hin + (size_t)b * HID * NV;
    const u16* ap  = hb  + (size_t)(wv*16 + m16)*NV + quad*8;
    const u16* bp0 = g_b + (size_t)(w0 + m16)*NV + quad*8;
    const u16* bp1 = g_b + (size_t)(w0 + 16 + m16)*NV + quad*8;
    f4 accA0 = {0.f,0.f,0.f,0.f}, accA1 = {0.f,0.f,0.f,0.f};
    #pragma unroll
    for (int k = 0; k < 32; ++k){
        bf8 a  = *(const bf8*)(ap  + k*32);
        bf8 b0 = *(const bf8*)(bp0 + k*32);
        bf8 b1 = *(const bf8*)(bp1 + k*32);
        accA0 = __builtin_amdgcn_mfma_f32_16x16x32_bf16(a, b0, accA0, 0, 0, 0);
        accA1 = __builtin_amdgcn_mfma_f32_16x16x32_bf16(a, b1, accA1, 0, 0, 0);
    }

    // ---- phase 0b: x_hat select + LDS publish (loads have long since landed) ----
    {
        float4 xh;
        xh.x = (__float_as_uint(xm.x) == 0x7f800000u) ? pv.x : xm.x;
        xh.y = (__float_as_uint(xm.y) == 0x7f800000u) ? pv.y : xm.y;
        xh.z = (__float_as_uint(xm.z) == 0x7f800000u) ? pv.z : xm.z;
        xh.w = (__float_as_uint(xm.w) == 0x7f800000u) ? pv.w : xm.w;
        *(float4*)&xh_s[v4] = xh;
    }
    // publish h_diff in bf16 for phase 3's B operand (cross-lane access needed)
    {
        int h4 = wv*16 + quad*4;
        #pragma unroll
        for (int wt = 0; wt < 2; ++wt){
            f4 a = wt ? accA1 : accA0;
            ushort4 pk;
            pk.x = f2bf(a[0]); pk.y = f2bf(a[1]); pk.z = f2bf(a[2]); pk.w = f2bf(a[3]);
            *(ushort4*)&hdb[wt*16 + m16][h4] = pk;
        }
    }
    __syncthreads();   // B1: xh_s + hdb ready

    // ---- phase 1: x_g[w] = sum_v x_hat[v] * ind_graph[w][v] (VALU + shfl reduce) ----
    {
        int w = tid >> 3, p = tid & 7;
        const u16* igr = ig_b + (size_t)(w0 + w) * NV;
        float acc = 0.f;
        for (int k = 0; k < 16; ++k){
            int v = p*8 + k*64;
            uint4 u = *(const uint4*)(igr + v);
            float gg[8]; cv8(u, gg);
            #pragma unroll
            for (int j = 0; j < 8; ++j) acc += gg[j] * xh_s[v + j];
        }
        acc += __shfl_xor(acc, 1);
        acc += __shfl_xor(acc, 2);
        acc += __shfl_xor(acc, 4);
        if (p == 0) xg_s[w] = acc;
    }

    // ---- phase 3: gates gh = W_hh . h_diff via MFMA (K=64) ----
    f4 accG[3][2];
    #pragma unroll
    for (int i = 0; i < 3; ++i){ accG[i][0] = (f4){0,0,0,0}; accG[i][1] = (f4){0,0,0,0}; }
    #pragma unroll
    for (int gi3 = 0; gi3 < 3; ++gi3){
        int g16 = gi3*64 + wv*16;
        #pragma unroll
        for (int ks = 0; ks < 2; ++ks){
            bf8 af = *(const bf8*)(whh_b + (size_t)(g16 + m16)*64 + ks*32 + quad*8);
            #pragma unroll
            for (int wt = 0; wt < 2; ++wt){
                bf8 bfr = *(const bf8*)&hdb[wt*16 + m16][ks*32 + quad*8];
                accG[gi3][wt] = __builtin_amdgcn_mfma_f32_16x16x32_bf16(af, bfr, accG[gi3][wt], 0, 0, 0);
            }
        }
    }
    __syncthreads();   // B2: xg_s ready

    // ---- phase 4: GRU elementwise (h_diff comes straight from accA registers) ----
    {
        int h4 = wv*16 + quad*4;
        #pragma unroll
        for (int wt = 0; wt < 2; ++wt){
            int w = wt*16 + m16;
            float xg = xg_s[w];
            f4 hd4 = wt ? accA1 : accA0;
            f4 hn4;
            #pragma unroll
            for (int r = 0; r < 4; ++r){
                int h = h4 + r;
                float ir  = xg * Wih[h]       + bih[h];
                float iz  = xg * Wih[64 + h]  + bih[64 + h];
                float inn = xg * Wih[128 + h] + bih[128 + h];
                float hr  = accG[0][wt][r] + bhh[h];
                float hz  = accG[1][wt][r] + bhh[64 + h];
                float hnn = accG[2][wt][r] + bhh[128 + h];
                float rg = 1.f / (1.f + __expf(-(ir + hr)));
                float zg = 1.f / (1.f + __expf(-(iz + hz)));
                float ng = tanhf(inn + rg * hnn);
                hn4[r] = (1.f - zg) * ng + zg * hd4[r];
            }
            *(f4*)&hnf[w][h4] = hn4;
        }
    }
    __syncthreads();   // B3: hnf ready

    // ---- phase 5: outputs ----
    {   // head partial dots over h (8 groups of 8)
        int w2 = tid & 31, hg = tid >> 5;
        float s1 = 0.f, s2 = 0.f;
        #pragma unroll
        for (int j = 0; j < 8; ++j){
            float hv = hnf[w2][hg*8 + j];
            s1 += Wini[hg*8 + j] * hv;
            s2 += Wo[hg*8 + j]   * hv;
        }
        r1[hg][w2] = s1; r2[hg][w2] = s2;
    }
    {   // h_out (bf16, coalesced) + reprs
        int h = tid >> 2, wq = tid & 3;
        float vals[8];
        #pragma unroll
        for (int j = 0; j < 8; ++j) vals[j] = hnf[wq*8 + j][h];
        u16 pk[8];
        #pragma unroll
        for (int j = 0; j < 8; ++j) pk[j] = f2bf(vals[j]);
        *(uint4*)(hout + (size_t)b*HID*NV + (size_t)h*NV + w0 + wq*8) = *(uint4*)pk;
        if (staged){
            float* rp = rtmp + (((size_t)t*BS + b)*HID + h)*NV + w0 + wq*8;
            float4 a = {vals[0], vals[1], vals[2], vals[3]};
            float4 c = {vals[4], vals[5], vals[6], vals[7]};
            *(float4*)rp       = a;
            *(float4*)(rp + 4) = c;
        } else {
            size_t rb = REPRS_OFF + (((size_t)b*HID + h)*NV + w0 + wq*8)*64 + t;
            #pragma unroll
            for (int j = 0; j < 8; ++j) out[rb + (size_t)j*64] = vals[j];
        }
    }
    __syncthreads();   // B4: r1/r2 ready
    if (tid < 32){
        int w = tid, wg = w0 + w;
        float s1 = 0.f, s2 = 0.f;
        #pragma unroll
        for (int hg = 0; hg < 8; ++hg){ s1 += r1[hg][w]; s2 += r2[hg][w]; }
        s1 += bini[0]; s2 += bo[0];
        size_t base = (size_t)b*65536 + (size_t)wg*64;
        out[IMPS_OFF + base + t] = s2;                 // imps[t] = W_out.h_new + b_out
        if (t < NSTEP - 1){
            out[PREDS_OFF + base + t + 1] = s1;        // preds[t+1]
            predsT[((size_t)b*NSTEP + t + 1)*NV + wg] = s1;
        }
    }
}

// ---------------- reprs staging [t][b][h][v] -> out [b][h][v][t] ----------------
__global__ void transpose_k(const float* __restrict__ rtmp, float* __restrict__ out){
    __shared__ float tile[64][65];
    int bh = blockIdx.x >> 4;          // 0..511 = b*64 + h
    int b  = bh >> 6, h = bh & 63;
    int v0 = (blockIdx.x & 15) << 6;
    int tid = threadIdx.x;
    int q = tid >> 6, l = tid & 63;
    #pragma unroll 4
    for (int r = 0; r < 16; ++r){
        int tt = r*4 + q;
        tile[tt][l] = rtmp[(((size_t)tt*BS + b)*HID + h)*NV + v0 + l];
    }
    __syncthreads();
    #pragma unroll 4
    for (int r = 0; r < 16; ++r){
        int vv = r*4 + q;
        out[REPRS_OFF + (((size_t)b*HID + h)*NV + v0 + vv)*64 + l] = tile[l][vv];
    }
}

extern "C" void kernel_launch(void* const* d_in, const int* in_sizes, int n_in,
                              void* d_out, int out_size, void* d_ws, size_t ws_size,
                              hipStream_t stream) {
    const float* x     = (const float*)d_in[0];
    const int*   mask  = (const int*)  d_in[1];
    const float* graph = (const float*)d_in[2];
    const float* ind   = (const float*)d_in[3];
    const float* h0    = (const float*)d_in[4];
    const float* Wini  = (const float*)d_in[5];
    const float* bini  = (const float*)d_in[6];
    const float* Wo    = (const float*)d_in[7];
    const float* bo    = (const float*)d_in[8];
    const float* Wih   = (const float*)d_in[9];
    const float* Whh   = (const float*)d_in[10];
    const float* bih   = (const float*)d_in[11];
    const float* bhh   = (const float*)d_in[12];
    float* out = (float*)d_out;

    char* ws = (char*)d_ws;
    u16*   hws    = (u16*)(ws);                         // 2 x 1 MB bf16 h ping-pong
    u16*   g_b    = (u16*)(ws + ((size_t)2<<20));       // 2 MB
    u16*   ig_b   = (u16*)(ws + ((size_t)4<<20));       // 2 MB
    u16*   whh_b  = (u16*)(ws + ((size_t)6<<20));       // 24 KB
    float* xmt    = (float*)(ws + ((size_t)7<<20));     // 2 MB  x/mask transposed+merged
    float* predsT = (float*)(ws + ((size_t)9<<20));     // 2 MB  preds in [b][t][v]
    float* rtmp   = (float*)(ws + ((size_t)12<<20));    // 128 MB reprs staging
    size_t need_staged = ((size_t)12<<20) + (size_t)NSTEP*BS*HID*NV*4;
    int staged = (ws_size >= need_staged) ? 1 : 0;

    conv_k<<<dim3(2048), dim3(256), 0, stream>>>(graph, ind, Whh, h0,
                                                 g_b, ig_b, whh_b, hws);
    prep_k<<<dim3(128), dim3(256), 0, stream>>>(x, mask, xmt);
    init_k<<<dim3(4), dim3(256), 0, stream>>>(h0, Wini, bini, out, predsT);
    for (int t = 0; t < NSTEP; ++t){
        const u16* hin  = hws + (size_t)(t & 1) * (BS*HID*NV);
        u16*       hout = hws + (size_t)((t+1) & 1) * (BS*HID*NV);
        step_k<<<dim3(256), dim3(256), 0, stream>>>(
            t, hin, hout, g_b, ig_b, whh_b, xmt, predsT,
            Wih, bih, bhh, Wini, bini, Wo, bo, out, rtmp, staged);
    }
    if (staged) transpose_k<<<dim3(8192), dim3(256), 0, stream>>>(rtmp, out);
}

// Round 3
// 1061.063 us; speedup vs baseline: 1.2645x; 1.2645x over previous
//
#include <hip/hip_runtime.h>
#include <hip/hip_bf16.h>

#define BS 8
#define HID 64
#define NV 1024
#define NSTEP 64
#define HSTRIDE (BS*HID*NV)   // elems per h ping-pong buffer (bf16)

// out layout (float32, concatenated flat, element offsets):
//   imps  [8][1][1024][64]  at 0
//   preds [8][1][1024][64]  at 524288
//   reprs [8][64][1024][64] at 1048576
#define IMPS_OFF  0
#define PREDS_OFF 524288
#define REPRS_OFF 1048576

typedef unsigned short u16;
typedef __attribute__((ext_vector_type(8))) short bf8;   // 8 bf16 = one MFMA operand
typedef __attribute__((ext_vector_type(4))) float f4;    // 4 f32 accumulator

__device__ __forceinline__ u16 f2bf(float f){
    __hip_bfloat16 h = __float2bfloat16(f);
    return *reinterpret_cast<u16*>(&h);
}
// read 8 f32 from global, pack to bf8
__device__ __forceinline__ bf8 ld8bf(const float* src){
    float v[8];
    *(float4*)&v[0] = *(const float4*)src;
    *(float4*)&v[4] = *(const float4*)(src + 4);
    union { u16 u[8]; bf8 b; } r;
    #pragma unroll
    for (int j = 0; j < 8; ++j) r.u[j] = f2bf(v[j]);
    return r.b;
}

// ---------------- h0 -> bf16 h fragments: hff[b][hh][k][sel][lane][8] ----------------
// semantic: h row = hh*32 + sel*16 + (lane&15), v = k*32 + (lane>>4)*8 + j
__global__ void conv_k(const float* __restrict__ h0, u16* __restrict__ hws){
    int f = blockIdx.x * blockDim.x + threadIdx.x;     // 65536 frags
    int l   = f & 63;
    int sel = (f >> 6) & 1;
    int k   = (f >> 7) & 31;
    int hh  = (f >> 12) & 1;
    // b = f >> 13 (implicit: same data broadcast, address is just f*8)
    int row = hh*32 + sel*16 + (l & 15);
    int col = k*32 + (l >> 4)*8;
    bf8 p = ld8bf(h0 + (size_t)row*NV + col);
    *(bf8*)(hws + (size_t)f*8) = p;
}

// ---------------- graph -> bf16 B-fragments: gff[tile][wt][k][lane][8] ----------------
// semantic: w row = tile*32 + wt*16 + (lane&15), v = k*32 + (lane>>4)*8 + j
__global__ void frag_k(const float* __restrict__ g, u16* __restrict__ gff){
    int f = blockIdx.x * blockDim.x + threadIdx.x;     // 131072 frags
    int l    = f & 63;
    int k    = (f >> 6) & 31;
    int wt   = (f >> 11) & 1;
    int tile = f >> 12;
    int row = tile*32 + wt*16 + (l & 15);
    int col = k*32 + (l >> 4)*8;
    bf8 p = ld8bf(g + (size_t)row*NV + col);
    *(bf8*)(gff + (size_t)f*8) = p;
}

// ---------------- pre-transpose x/mask: xmt[b][t][v] = mask ? x : +INF ----------------
__global__ void prep_k(const float* __restrict__ x, const int* __restrict__ mask,
                       float* __restrict__ xmt){
    __shared__ float tx[64][65];
    __shared__ int   tm[64][65];
    int b  = blockIdx.x >> 4;
    int v0 = (blockIdx.x & 15) << 6;
    int tid = threadIdx.x;
    int q = tid >> 6, l = tid & 63;
    #pragma unroll 4
    for (int r = 0; r < 16; ++r){
        int vv = r*4 + q;
        size_t idx = ((size_t)b*NV + v0 + vv)*64 + l;   // x[b][0][v][t], coalesced in t
        tx[vv][l] = x[idx];
        tm[vv][l] = mask[idx];
    }
    __syncthreads();
    #pragma unroll 4
    for (int r = 0; r < 16; ++r){
        int tt = r*4 + q;
        float xv = tx[l][tt];
        xmt[((size_t)b*NSTEP + tt)*NV + v0 + l] = tm[l][tt] ? xv : __builtin_inff();
    }
}

// ---------------- preds[t=0] = W_init . h0 + b_init ----------------
__global__ void init_k(const float* __restrict__ h0, const float* __restrict__ Wini,
                       const float* __restrict__ bini, float* __restrict__ out,
                       float* __restrict__ predsT){
    int v = blockIdx.x * blockDim.x + threadIdx.x;
    if (v < NV){
        float s = 0.f;
        for (int h = 0; h < HID; ++h) s += h0[h*NV + v] * Wini[h];
        s += bini[0];
        for (int b = 0; b < BS; ++b){
            out[PREDS_OFF + (size_t)b*65536 + (size_t)v*64] = s;
            predsT[(size_t)b*NSTEP*NV + v] = s;
        }
    }
}

// ---------------- one recurrence step: frag-coalesced, barrier-light ----------------
// grid: 256 blocks = 8 batches x 32 node-tiles, 256 threads = 4 waves (2 wt x 2 hh)
__global__ __launch_bounds__(256, 1) void step_k(
    int t,
    const u16* __restrict__ hin, u16* __restrict__ hout,
    const u16* __restrict__ gff, const float* __restrict__ ig,
    const float* __restrict__ Whh,
    const float* __restrict__ xmt, float* __restrict__ predsT,
    const float* __restrict__ Wih, const float* __restrict__ bih,
    const float* __restrict__ bhh,
    const float* __restrict__ Wini, const float* __restrict__ bini,
    const float* __restrict__ Wo, const float* __restrict__ bo,
    float* out, float* __restrict__ rtmp, int staged)
{
    __shared__ float xh_s[NV];                  // 4 KB
    __shared__ __align__(16) u16 hdb[32][72];   // 4.6 KB  h_diff bf16 [w][h]
    __shared__ __align__(16) float hnf[32][68]; // 8.5 KB  h_new  f32 [w][h]
    __shared__ float xg_s[32];
    __shared__ float r1[8][33], r2[8][33];

    const int tid  = threadIdx.x;
    const int b    = blockIdx.x >> 5;           // batch
    const int tile = blockIdx.x & 31;           // node tile (XCD-friendly: tile%8 = XCD)
    const int w0   = tile << 5;
    const int lane = tid & 63;
    const int wv   = tid >> 6;
    const int wt   = wv & 1;                    // w 16-tile
    const int hh   = wv >> 1;                   // h 32-half
    const int m16  = lane & 15;
    const int q    = lane >> 4;

    // ---- phase 0a: coalesced x/preds loads (consumed after MFMA stream) ----
    const int v4 = tid * 4;
    float4 xm = *(const float4*)(xmt    + ((size_t)b*NSTEP + t)*NV + v4);
    float4 pv = *(const float4*)(predsT + ((size_t)b*NSTEP + t)*NV + v4);

    // ---- phase 2: h_diff = h . graph^T, all operands frag-coalesced 1KB wave loads ----
    const u16* hA = hin + (size_t)b*65536 + (size_t)hh*32768 + lane*8;
    const u16* gB = gff + ((size_t)(tile*2 + wt)*32)*512 + lane*8;
    f4 accA0 = {0.f,0.f,0.f,0.f}, accA1 = {0.f,0.f,0.f,0.f};
    #pragma unroll
    for (int k = 0; k < 32; ++k){
        bf8 a0 = *(const bf8*)(hA + k*1024);          // sel=0: h rows hh*32 + 0..15
        bf8 a1 = *(const bf8*)(hA + k*1024 + 512);    // sel=1: h rows hh*32 + 16..31
        bf8 gb = *(const bf8*)(gB + k*512);
        accA0 = __builtin_amdgcn_mfma_f32_16x16x32_bf16(a0, gb, accA0, 0, 0, 0);
        accA1 = __builtin_amdgcn_mfma_f32_16x16x32_bf16(a1, gb, accA1, 0, 0, 0);
    }
    // acc layout: col = m16 -> w = wt*16+m16 ; row = q*4+r -> h = hh*32 + sel*16 + q*4+r

    // ---- W_hh fragments (per-launch, loaded once, used in phase 3) ----
    bf8 wf[3][2];
    #pragma unroll
    for (int gi = 0; gi < 3; ++gi)
        #pragma unroll
        for (int ht = 0; ht < 2; ++ht)
            wf[gi][ht] = ld8bf(Whh + (size_t)(gi*64 + hh*32 + ht*16 + m16)*64 + q*8);
    // note: wf holds K-slice q*8..q*8+8 of rows; full K=64 covered below via ks loop reload

    // ---- phase 0b: x_hat select + h_diff publish ----
    {
        float4 xh;
        xh.x = (__float_as_uint(xm.x) == 0x7f800000u) ? pv.x : xm.x;
        xh.y = (__float_as_uint(xm.y) == 0x7f800000u) ? pv.y : xm.y;
        xh.z = (__float_as_uint(xm.z) == 0x7f800000u) ? pv.z : xm.z;
        xh.w = (__float_as_uint(xm.w) == 0x7f800000u) ? pv.w : xm.w;
        *(float4*)&xh_s[v4] = xh;
    }
    #pragma unroll
    for (int ht = 0; ht < 2; ++ht){
        f4 a = ht ? accA1 : accA0;
        ushort4 pk;
        pk.x = f2bf(a[0]); pk.y = f2bf(a[1]); pk.z = f2bf(a[2]); pk.w = f2bf(a[3]);
        *(ushort4*)&hdb[wt*16 + m16][hh*32 + ht*16 + q*4] = pk;
    }
    __syncthreads();   // B1: xh_s + hdb ready

    // ---- phase 1: x_g[w] = sum_v ig[w][v]*x_hat[v] (f32 direct, shfl reduce) ----
    {
        int w = tid >> 3, p = tid & 7;
        const float* igr = ig + (size_t)(w0 + w)*NV + p*8;
        float acc = 0.f;
        #pragma unroll
        for (int k = 0; k < 16; ++k){
            float4 ga = *(const float4*)(igr + k*64);
            float4 gc = *(const float4*)(igr + k*64 + 4);
            const float* xv = &xh_s[p*8 + k*64];
            acc += ga.x*xv[0] + ga.y*xv[1] + ga.z*xv[2] + ga.w*xv[3]
                 + gc.x*xv[4] + gc.y*xv[5] + gc.z*xv[6] + gc.w*xv[7];
        }
        acc += __shfl_xor(acc, 1);
        acc += __shfl_xor(acc, 2);
        acc += __shfl_xor(acc, 4);
        if (p == 0) xg_s[w] = acc;
    }

    // ---- phase 3: gh = W_hh . h_diff (K=64): A from Whh frags, B from hdb ----
    f4 accG[3][2];
    #pragma unroll
    for (int i = 0; i < 3; ++i){ accG[i][0] = (f4){0,0,0,0}; accG[i][1] = (f4){0,0,0,0}; }
    #pragma unroll
    for (int ks = 0; ks < 2; ++ks){
        bf8 bfr = *(const bf8*)&hdb[wt*16 + m16][ks*32 + q*8];
        #pragma unroll
        for (int gi = 0; gi < 3; ++gi){
            #pragma unroll
            for (int ht = 0; ht < 2; ++ht){
                bf8 af = (ks == 0) ? wf[gi][ht]
                       : ld8bf(Whh + (size_t)(gi*64 + hh*32 + ht*16 + m16)*64 + 32 + q*8);
                accG[gi][ht] = __builtin_amdgcn_mfma_f32_16x16x32_bf16(af, bfr, accG[gi][ht], 0, 0, 0);
            }
        }
    }
    __syncthreads();   // B2: xg_s ready

    // ---- phase 4: GRU elementwise (h_diff straight from accA regs) ----
    {
        int wme = wt*16 + m16;
        float xg = xg_s[wme];
        #pragma unroll
        for (int ht = 0; ht < 2; ++ht){
            f4 hd4 = ht ? accA1 : accA0;
            f4 hn4;
            int hb4 = hh*32 + ht*16 + q*4;
            #pragma unroll
            for (int r = 0; r < 4; ++r){
                int h = hb4 + r;
                float ir  = xg * Wih[h]       + bih[h];
                float iz  = xg * Wih[64 + h]  + bih[64 + h];
                float inn = xg * Wih[128 + h] + bih[128 + h];
                float hr  = accG[0][ht][r] + bhh[h];
                float hz  = accG[1][ht][r] + bhh[64 + h];
                float hnn = accG[2][ht][r] + bhh[128 + h];
                float rg = 1.f / (1.f + __expf(-(ir + hr)));
                float zg = 1.f / (1.f + __expf(-(iz + hz)));
                float ng = tanhf(inn + rg * hnn);
                hn4[r] = (1.f - zg) * ng + zg * hd4[r];
            }
            *(f4*)&hnf[wme][hb4] = hn4;
        }
    }
    __syncthreads();   // B3: hnf ready

    // ---- phase 5: outputs ----
    {   // head partial dots over h (8 groups of 8)
        int w2 = tid & 31, hg = tid >> 5;
        float s1 = 0.f, s2 = 0.f;
        #pragma unroll
        for (int j = 0; j < 8; ++j){
            float hv = hnf[w2][hg*8 + j];
            s1 += Wini[hg*8 + j] * hv;
            s2 += Wo[hg*8 + j]   * hv;
        }
        r1[hg][w2] = s1; r2[hg][w2] = s2;
    }
    {   // h_out written in FRAGMENT order (1KB contiguous per wave) + reprs staging
        int h = tid >> 2, wq = tid & 3;
        float vals[8];
        #pragma unroll
        for (int j = 0; j < 8; ++j) vals[j] = hnf[wq*8 + j][h];
        u16 pk[8];
        #pragma unroll
        for (int j = 0; j < 8; ++j) pk[j] = f2bf(vals[j]);
        // hff addr: b*65536 + (((h>>5)*32 + tile)*2 + ((h>>4)&1))*512 + wq*128 + (h&15)*8
        size_t ho = (size_t)b*65536
                  + ((size_t)((h >> 5)*32 + tile)*2 + ((h >> 4) & 1))*512
                  + wq*128 + (h & 15)*8;
        *(uint4*)(hout + ho) = *(uint4*)pk;
        if (staged){
            float* rp = rtmp + (((size_t)t*BS + b)*HID + h)*NV + w0 + wq*8;
            float4 a = {vals[0], vals[1], vals[2], vals[3]};
            float4 c = {vals[4], vals[5], vals[6], vals[7]};
            *(float4*)rp       = a;
            *(float4*)(rp + 4) = c;
        } else {
            size_t rb = REPRS_OFF + (((size_t)b*HID + h)*NV + w0 + wq*8)*64 + t;
            #pragma unroll
            for (int j = 0; j < 8; ++j) out[rb + (size_t)j*64] = vals[j];
        }
    }
    __syncthreads();   // B4: r1/r2 ready
    if (tid < 32){
        int w = tid, wg = w0 + w;
        float s1 = 0.f, s2 = 0.f;
        #pragma unroll
        for (int hg = 0; hg < 8; ++hg){ s1 += r1[hg][w]; s2 += r2[hg][w]; }
        s1 += bini[0]; s2 += bo[0];
        size_t base = (size_t)b*65536 + (size_t)wg*64;
        out[IMPS_OFF + base + t] = s2;                 // imps[t] = W_out.h_{t+1} + b_out
        if (t < NSTEP - 1){
            out[PREDS_OFF + base + t + 1] = s1;        // preds[t+1] = W_init.h_{t+1}
            predsT[((size_t)b*NSTEP + t + 1)*NV + wg] = s1;
        }
    }
}

// ---------------- reprs staging [t][b][h][v] -> out [b][h][v][t] ----------------
__global__ void transpose_k(const float* __restrict__ rtmp, float* __restrict__ out){
    __shared__ float tile[64][65];
    int bh = blockIdx.x >> 4;          // 0..511 = b*64 + h
    int b  = bh >> 6, h = bh & 63;
    int v0 = (blockIdx.x & 15) << 6;
    int tid = threadIdx.x;
    int q = tid >> 6, l = tid & 63;
    #pragma unroll 4
    for (int r = 0; r < 16; ++r){
        int tt = r*4 + q;
        tile[tt][l] = rtmp[(((size_t)tt*BS + b)*HID + h)*NV + v0 + l];
    }
    __syncthreads();
    #pragma unroll 4
    for (int r = 0; r < 16; ++r){
        int vv = r*4 + q;
        out[REPRS_OFF + (((size_t)b*HID + h)*NV + v0 + vv)*64 + l] = tile[l][vv];
    }
}

extern "C" void kernel_launch(void* const* d_in, const int* in_sizes, int n_in,
                              void* d_out, int out_size, void* d_ws, size_t ws_size,
                              hipStream_t stream) {
    const float* x     = (const float*)d_in[0];
    const int*   mask  = (const int*)  d_in[1];
    const float* graph = (const float*)d_in[2];
    const float* ind   = (const float*)d_in[3];
    const float* h0    = (const float*)d_in[4];
    const float* Wini  = (const float*)d_in[5];
    const float* bini  = (const float*)d_in[6];
    const float* Wo    = (const float*)d_in[7];
    const float* bo    = (const float*)d_in[8];
    const float* Wih   = (const float*)d_in[9];
    const float* Whh   = (const float*)d_in[10];
    const float* bih   = (const float*)d_in[11];
    const float* bhh   = (const float*)d_in[12];
    float* out = (float*)d_out;

    char* ws = (char*)d_ws;
    u16*   hws    = (u16*)(ws);                         // 2 x 1 MB bf16 h frags ping-pong
    u16*   gff    = (u16*)(ws + ((size_t)2<<20));       // 2 MB graph B-frags
    float* xmt    = (float*)(ws + ((size_t)4<<20));     // 2 MB x/mask merged transposed
    float* predsT = (float*)(ws + ((size_t)6<<20));     // 2 MB preds in [b][t][v]
    float* rtmp   = (float*)(ws + ((size_t)8<<20));     // 128 MB reprs staging
    size_t need_staged = ((size_t)8<<20) + (size_t)NSTEP*BS*HID*NV*4;
    int staged = (ws_size >= need_staged) ? 1 : 0;

    conv_k<<<dim3(256), dim3(256), 0, stream>>>(h0, hws);
    frag_k<<<dim3(512), dim3(256), 0, stream>>>(graph, gff);
    prep_k<<<dim3(128), dim3(256), 0, stream>>>(x, mask, xmt);
    init_k<<<dim3(4), dim3(256), 0, stream>>>(h0, Wini, bini, out, predsT);
    for (int t = 0; t < NSTEP; ++t){
        const u16* hin  = hws + (size_t)(t & 1) * HSTRIDE;
        u16*       hout = hws + (size_t)((t+1) & 1) * HSTRIDE;
        step_k<<<dim3(256), dim3(256), 0, stream>>>(
            t, hin, hout, gff, ind, Whh, xmt, predsT,
            Wih, bih, bhh, Wini, bini, Wo, bo, out, rtmp, staged);
    }
    if (staged) transpose_k<<<dim3(8192), dim3(256), 0, stream>>>(rtmp, out);
}